// Round 1
// baseline (309.341 us; speedup 1.0000x reference)
//
#include <hip/hip_runtime.h>

// StructuredLinear: out[b,o] = sum_i x[b,i] * weight[o,i] * mask[o,i]
// mask[o,i] = (o/64 == i/64)  -> 64 independent 64x64 diagonal-block GEMMs.
// x: [8192, 4096] fp32, weight: [4096, 4096] fp32, out: [8192, 4096] fp32.
// Memory-bound: ~270 MB moved, ~43 us floor @ 6.3 TB/s. fp32 vector-FMA
// compute floor ~27 us (no fp32 MFMA on CDNA4) -> need decent FMA efficiency.

constexpr int IN_F  = 4096;
constexpr int OUT_F = 4096;
constexpr int BLK   = 64;   // mask block size (both dims)
constexpr int NBLK  = 64;   // number of diagonal blocks
constexpr int TROWS = 64;   // rows of x per workgroup tile
constexpr int PADS  = 68;   // LDS row stride (floats); +4 pad keeps 16B align,
                            // makes rows-4-apart land on banks {0,16} (2-way = free)

__global__ __launch_bounds__(256, 4)
void block_diag_gemm(const float* __restrict__ x,
                     const float* __restrict__ w,
                     float* __restrict__ out)
{
    __shared__ float xs[TROWS][PADS];
    __shared__ float ws[BLK][PADS];

    const int blk = blockIdx.y;            // diagonal block 0..63
    const int r0  = blockIdx.x * TROWS;    // row-tile base
    const int c0  = blk * BLK;             // both the in-col and out-col base

    const int tid  = threadIdx.x;
    const int lrow = tid >> 4;             // 0..15
    const int lcol = (tid & 15) << 2;      // 0,4,...,60

    // ---- stage x tile (64x64) and w diagonal block (64x64) into LDS ----
    // Each wave loads 4 full 256B rows per instruction -> fully coalesced.
#pragma unroll
    for (int k = 0; k < 4; ++k) {
        const int rr = lrow + k * 16;
        const float4 xv = *reinterpret_cast<const float4*>(
            &x[(size_t)(r0 + rr) * IN_F + c0 + lcol]);
        *reinterpret_cast<float4*>(&xs[rr][lcol]) = xv;
        const float4 wv = *reinterpret_cast<const float4*>(
            &w[(size_t)(c0 + rr) * IN_F + c0 + lcol]);
        *reinterpret_cast<float4*>(&ws[rr][lcol]) = wv;
    }
    __syncthreads();

    // Thread tile: 4 consecutive rows x 4 stride-16 outputs.
    // Row group rg..rg+3 (rows 4 apart across lanes -> 2-way LDS, free).
    // Output set {og, og+16, og+32, og+48}: each ws read instruction hits 16
    // CONSECUTIVE rows (lanes og=0..15) -> bank stride 4 -> 2-way, free.
    const int rg = (tid >> 4) << 2;
    const int og = tid & 15;

    float acc[4][4] = {};  // acc[rr][oo]

#pragma unroll 4
    for (int i = 0; i < BLK; i += 4) {
        float4 xv[4], wv[4];
#pragma unroll
        for (int rr = 0; rr < 4; ++rr)
            xv[rr] = *reinterpret_cast<const float4*>(&xs[rg + rr][i]);
#pragma unroll
        for (int oo = 0; oo < 4; ++oo)
            wv[oo] = *reinterpret_cast<const float4*>(&ws[og + oo * 16][i]);
#pragma unroll
        for (int rr = 0; rr < 4; ++rr)
#pragma unroll
            for (int oo = 0; oo < 4; ++oo) {
                acc[rr][oo] += xv[rr].x * wv[oo].x;
                acc[rr][oo] += xv[rr].y * wv[oo].y;
                acc[rr][oo] += xv[rr].z * wv[oo].z;
                acc[rr][oo] += xv[rr].w * wv[oo].w;
            }
    }

    // ---- epilogue: out[r0+rg+rr][c0 + og + 16*oo] ----
    // Per store instruction: 4 segments of 16 consecutive floats (64B) -> OK.
#pragma unroll
    for (int rr = 0; rr < 4; ++rr) {
        float* orow = &out[(size_t)(r0 + rg + rr) * OUT_F + c0];
#pragma unroll
        for (int oo = 0; oo < 4; ++oo)
            orow[og + oo * 16] = acc[rr][oo];
    }
}

extern "C" void kernel_launch(void* const* d_in, const int* in_sizes, int n_in,
                              void* d_out, int out_size, void* d_ws, size_t ws_size,
                              hipStream_t stream) {
    const float* x = (const float*)d_in[0];
    const float* w = (const float*)d_in[1];
    // d_in[2] is the mask; its structure (64x64 block-diagonal) is baked in.
    float* out = (float*)d_out;

    const int nrows = in_sizes[0] / IN_F;      // 8192
    dim3 grid(nrows / TROWS, NBLK);            // 128 x 64
    block_diag_gemm<<<grid, dim3(256, 1, 1), 0, stream>>>(x, w, out);
}